// Round 8
// baseline (68.715 us; speedup 1.0000x reference)
//
#include <hip/hip_runtime.h>
#include <hip/hip_bf16.h>

// SConv2dAvg: stride-2 conv with per-output-pixel stochastic tap selection.
// B=32 C=128 H=W=64, O=256 kh=kw=3, oh=ow=32, PAD=1, STRIDE=2.
//
// Structure (round 8):
//  1) prep (fused): weight fp32 -> bf16 wpre[9][256][128] (per-tap slices,
//     16B-chunk XOR swizzle baked: chunk' = chunk ^ (o&15)); input NCHW fp32
//     -> bf16 padded NHWC tp[32][66][66][128] (zero halo, no bounds checks).
//  2) sconv_mfma8: implicit GEMM, block = 64o x 128pix, 256 thr / 4 waves,
//     grid 1024 = 4 blocks/CU. K-loop = 9 taps (K-step 128), 32 MFMA/barrier.
//     B (weights): LDS 2-buffer, staged 1 tap ahead via global_load_lds.
//     A (pixels): direct global->VGPR, double-buffered ARa/ARb (named sets).
//     Sync: ONE __syncthreads() per tap — full drain, robust to spills
//     (R7's hand-counted vmcnt raced when extra vmem ops shifted the count).

typedef short bf16x8 __attribute__((ext_vector_type(8)));
typedef float f32x4  __attribute__((ext_vector_type(4)));

#define WPRE_BYTES (9 * 256 * 128 * 2)              // 589824
#define TRANS_BYTES (32 * 66 * 66 * 128 * 2)        // 35684352
#define TOTAL_WS (WPRE_BYTES + TRANS_BYTES)

__device__ __forceinline__ unsigned short f2bf(float x) {
  unsigned u = __float_as_uint(x);
  return (unsigned short)((u + 0x7fffu + ((u >> 16) & 1u)) >> 16);
}
__device__ __forceinline__ unsigned pk2(float a, float b) {
  unsigned ua = __float_as_uint(a), ub = __float_as_uint(b);
  return ((ua + 0x7fffu + ((ua >> 16) & 1u)) >> 16) |
         ((ub + 0x7fffu + ((ub >> 16) & 1u)) & 0xffff0000u);
}
__device__ __forceinline__ bf16x8 ld_frag(const uint4* a) {
  union { uint4 u; bf16x8 s; } cv; cv.u = *a; return cv.s;
}
__device__ __forceinline__ void async16(const void* g, void* l) {
  __builtin_amdgcn_global_load_lds(
      (__attribute__((address_space(1))) void*)(void*)g,
      (__attribute__((address_space(3))) void*)l, 16, 0, 0);
}

// ---------------- fused pre-pass: transform + wprep ------------------------
// grid (102, 32): x < 66 -> padded-NHWC transform of (row hp=x, batch y);
//                 x >= 66 -> wprep: linear elem L = ((x-66)*32+y)*256+tid.
__global__ __launch_bounds__(256) void prep(const float* __restrict__ in,
                                            const float* __restrict__ w,
                                            unsigned short* __restrict__ tp,
                                            unsigned short* __restrict__ wpre) {
  const int tid = threadIdx.x;
  if (blockIdx.x >= 66) {   // ---- weight prep: wpre[tap][o][128], swz baked
    const int L    = ((((blockIdx.x - 66) << 5) + blockIdx.y) << 8) + tid;
    const int k_in = L & 127;
    const int o    = (L >> 7) & 255;
    const int tap  = L >> 15;                       // 0..8
    const int c    = (((k_in >> 3) ^ (o & 15)) << 3) + (k_in & 7);
    wpre[L] = f2bf(w[(o * 128 + c) * 9 + tap]);
    return;
  }
  // ---- input transform ----
  __shared__ float lds[128 * 65];
  const int hp = blockIdx.x;   // 0..65 padded row
  const int b  = blockIdx.y;
  uint4* rowp = (uint4*)(tp + (size_t)(b * 66 + hp) * 66 * 128);
  uint4 z; z.x = z.y = z.z = z.w = 0u;
  if (hp == 0 || hp == 65) {                 // zero border rows
    for (int s = tid; s < 1056; s += 256) rowp[s] = z;
    return;
  }
  const int h = hp - 1;
  const float* src = in + ((size_t)b << 19) + (h << 6);
  const int ww4 = (tid & 15) << 2;
  const int c0  = tid >> 4;
#pragma unroll
  for (int pass = 0; pass < 8; ++pass) {
    int c = (pass << 4) + c0;
    float4 v = *(const float4*)(src + ((size_t)c << 12) + ww4);  // coalesced
    float* lp = lds + c * 65 + ww4;
    lp[0] = v.x; lp[1] = v.y; lp[2] = v.z; lp[3] = v.w;
  }
  __syncthreads();
  for (int s = tid; s < 1056; s += 256) {
    if (s < 16 || s >= 1040) { rowp[s] = z; continue; }   // zero border cols
    int idx = s - 16;
    int wq = idx >> 4, c8 = idx & 15;
    const float* lp = lds + (c8 << 3) * 65 + wq;
    uint4 d;
    d.x = pk2(lp[0],   lp[65]);
    d.y = pk2(lp[130], lp[195]);
    d.z = pk2(lp[260], lp[325]);
    d.w = pk2(lp[390], lp[455]);
    rowp[s] = d;
  }
}

// ----------------------------- main kernel ---------------------------------
__global__ __launch_bounds__(256, 4) void sconv_mfma8(
    const unsigned short* __restrict__ tp,   // [32][66][66][128] bf16 padded
    const unsigned short* __restrict__ wpre, // [9][256][128] bf16 pre-swizzled
    const float* __restrict__ bias,
    const int* __restrict__ selh,            // [32][32]
    const int* __restrict__ selw,            // [32][32]
    float* __restrict__ out)                 // [32][256][32][32]
{
  __shared__ uint4 Blds[2][1024];   // weights [o_local(64)][16 chunks], 16KB/buf
  __shared__ float bias_s[64];

  const int tid = threadIdx.x;
  // XCD-chunked swizzle (T1): 1024 = 8 XCDs x 128 consecutive logical tiles
  const int d0  = blockIdx.x;
  const int blk = ((d0 & 7) << 7) | (d0 >> 3);
  const int b   = blk >> 5;                 // batch
  const int y0  = ((blk >> 2) & 7) << 2;    // 4 output rows
  const int oq  = blk & 3;                  // o-quarter (64 o's)

  if (tid < 64) bias_s[tid] = bias[(oq << 6) + tid];

  const int wv = tid >> 6, ln = tid & 63;
  const int lo = ln & 15, hi = ln >> 4;

  // ---- A (pixels): lane (lo,hi) owns 16B chunk hi of pixel rows P0,P1
  size_t apix0, apix1;              // byte offset into tp at tap (0,0)
  {
#pragma unroll
    for (int f = 0; f < 2; ++f) {
      const int P  = (wv << 5) + (f << 4) + lo;   // block pixel 0..127
      const int py = y0 + (P >> 5);
      const int px = P & 31;
      const int addr = (b * 66 + 2 * py + selh[(py << 5) | px]) * 66
                     + 2 * px + selw[(py << 5) | px];
      const size_t v = ((size_t)addr << 8) + (hi << 4);
      if (f == 0) apix0 = v; else apix1 = v;
    }
  }
  const char* tbase = (const char*)tp;
  const char* wbase = (const char*)wpre + (oq << 14);   // this block's 64-o slice

  f32x4 acc[4][2] = {};             // [o-frag][pix-frag]
  bf16x8 ARa[2][4], ARb[2][4];      // A regs, two named sets (static idx only)

#define STAGE_B(BUF, T)                                                       \
  do {                                                                        \
    _Pragma("unroll")                                                         \
    for (int r = 0; r < 4; ++r)   /* 4 x 4KB: 16KB tap slice, linear */       \
      async16(wbase + ((T) << 16) + (((wv << 2) + r) << 10) + (ln << 4),      \
              &Blds[BUF][((wv << 2) + r) << 6]);                              \
  } while (0)

#define LOADA(AR, T)                                                          \
  do {                                                                        \
    const int toff_ = (((T) / 3) * 66 + ((T) % 3)) << 8;                      \
    _Pragma("unroll")                                                         \
    for (int ks = 0; ks < 4; ++ks) {                                          \
      AR[0][ks] = *(const bf16x8*)(tbase + apix0 + toff_ + (ks << 6));        \
      AR[1][ks] = *(const bf16x8*)(tbase + apix1 + toff_ + (ks << 6));        \
    }                                                                         \
  } while (0)

#define COMPUTE(BUF, AR)                                                      \
  do {                                                                        \
    const uint4* B_ = &Blds[BUF][0];                                          \
    _Pragma("unroll")                                                         \
    for (int ks = 0; ks < 4; ++ks) {                                          \
      bf16x8 FW[4];                                                           \
      _Pragma("unroll")                                                       \
      for (int fo = 0; fo < 4; ++fo)   /* row=o_local, chunk XOR-swizzled */  \
        FW[fo] = ld_frag(B_ + ((fo << 8) + (lo << 4)) + (((ks << 2) + hi) ^ lo)); \
      __builtin_amdgcn_s_setprio(1);                                          \
      _Pragma("unroll")                                                       \
      for (int fo = 0; fo < 4; ++fo) {                                        \
        acc[fo][0] = __builtin_amdgcn_mfma_f32_16x16x32_bf16(                 \
            FW[fo], AR[0][ks], acc[fo][0], 0, 0, 0);                          \
        acc[fo][1] = __builtin_amdgcn_mfma_f32_16x16x32_bf16(                 \
            FW[fo], AR[1][ks], acc[fo][1], 0, 0, 0);                          \
      }                                                                       \
      __builtin_amdgcn_s_setprio(0);                                          \
    }                                                                         \
  } while (0)

  // prologue: tap 0 into buf0 / ARa, fully landed by the syncthreads
  STAGE_B(0, 0);
  LOADA(ARa, 0);
  __syncthreads();                  // drains vmcnt(0)+lgkmcnt(0): B0, A0 ready

  // steady loop: 1-tap-ahead prefetch, one full-drain barrier per tap.
  // Safety does NOT depend on any vmem count (robust to spills):
  //  - STAGE_B(t+1) targets the buffer NOT read by COMPUTE(t);
  //  - end-of-iter __syncthreads publishes B(t+1)/A(t+1) and protects reuse.
#pragma unroll
  for (int tt = 0; tt < 4; ++tt) {
    const int t0 = tt << 1;
    STAGE_B(1, t0 + 1);             // prefetch next tap into other buffer
    LOADA(ARb, t0 + 1);
    COMPUTE(0, ARa);                // 16 ds_read + 32 MFMA on current tap
    __syncthreads();

    STAGE_B(0, t0 + 2);
    LOADA(ARa, t0 + 2);
    COMPUTE(1, ARb);
    __syncthreads();
  }
  COMPUTE(0, ARa);                  // tap 8
#undef STAGE_B
#undef LOADA
#undef COMPUTE

  // ---- epilogue: D row = o_local (fo*16 + hi*4 + j), col = pix; +bias
  float* ob = out + ((size_t)b << 18) + ((size_t)oq << 16) + (y0 << 5);
#pragma unroll
  for (int fo = 0; fo < 4; ++fo) {
    const int obase = (fo << 4) + (hi << 2);
#pragma unroll
    for (int f = 0; f < 2; ++f) {
      const int P = (wv << 5) + (f << 4) + lo;
#pragma unroll
      for (int j = 0; j < 4; ++j) {
        const int o = obase + j;
        ob[((size_t)o << 10) + P] = acc[fo][f][j] + bias_s[o];
      }
    }
  }
}

// ------------------- exact fp32 fallback (ws too small) --------------------
__global__ __launch_bounds__(256) void sconv_naive(
    const float* __restrict__ in, const float* __restrict__ w,
    const float* __restrict__ bias, const int* __restrict__ selh,
    const int* __restrict__ selw, float* __restrict__ out) {
  int idx = (blockIdx.x << 8) + threadIdx.x;
  if (idx >= 32 * 256 * 32 * 32) return;
  int x = idx & 31, y = (idx >> 5) & 31, o = (idx >> 10) & 255, b = idx >> 18;
  int rh0 = 2 * y + selh[(y << 5) | x] - 1;
  int rw0 = 2 * x + selw[(y << 5) | x] - 1;
  const float* inb = in + ((size_t)b << 19);
  const float* wo_ = w + o * 1152;
  float acc = bias[o];
  for (int c = 0; c < 128; ++c)
    for (int i = 0; i < 3; ++i) {
      int rh = rh0 + i;
      if (rh < 0 || rh >= 64) continue;
      for (int j = 0; j < 3; ++j) {
        int rw = rw0 + j;
        if (rw < 0 || rw >= 64) continue;
        acc += inb[(c << 12) + (rh << 6) + rw] * wo_[c * 9 + i * 3 + j];
      }
    }
  out[idx] = acc;
}

extern "C" void kernel_launch(void* const* d_in, const int* in_sizes, int n_in,
                              void* d_out, int out_size, void* d_ws, size_t ws_size,
                              hipStream_t stream) {
  const float* in   = (const float*)d_in[0];
  const float* w    = (const float*)d_in[1];
  const float* bias = (const float*)d_in[2];
  const int*   selh = (const int*)d_in[3];
  const int*   selw = (const int*)d_in[4];
  float* out = (float*)d_out;

  if (ws_size >= (size_t)TOTAL_WS) {
    unsigned short* wpre = (unsigned short*)d_ws;
    unsigned short* tp   = (unsigned short*)((char*)d_ws + WPRE_BYTES);
    prep<<<dim3(102, 32), dim3(256), 0, stream>>>(in, w, tp, wpre);
    sconv_mfma8<<<dim3(1024), dim3(256), 0, stream>>>(tp, wpre, bias, selh, selw, out);
  } else {
    sconv_naive<<<dim3(32768), dim3(256), 0, stream>>>(in, w, bias, selh, selw, out);
  }
}

// Round 9
// 51.582 us; speedup vs baseline: 1.3321x; 1.3321x over previous
//
#include <hip/hip_runtime.h>
#include <hip/hip_bf16.h>

// SConv2dAvg: stride-2 conv with per-output-pixel stochastic tap selection.
// B=32 C=128 H=W=64, O=256 kh=kw=3, oh=ow=32, PAD=1, STRIDE=2.
//
// Round 9 structure:
//  prep (fused): weight fp32 -> bf16 wpre[18][256][8chunk][8] (K-step 64,
//    chunk-pos XOR (o&7) baked); input NCHW fp32 -> bf16 padded NHWC
//    tp[32][66][66][128] (zero halo).
//  sconv_mfma9: block = 256o x 128pix (A read EXACTLY once; per-CU L2 traffic
//    0.86 MB), grid 256 = 1 block/CU, 512 thr / 8 waves, wave tile 64o x 64pix.
//    K-step 64 (128B rows, no line waste). LDS 2-buf (A 16K + B 32K) = 97 KB.
//    K-loop vmem = global_load_lds ONLY -> exact counted vmcnt(6) (R4-proven;
//    R7/R8 lesson: ordinary loads/drains break the count or the overlap).

typedef short bf16x8 __attribute__((ext_vector_type(8)));
typedef float f32x4  __attribute__((ext_vector_type(4)));

#define WPRE_BYTES (18 * 256 * 64 * 2)              // 589824
#define TRANS_BYTES (32 * 66 * 66 * 128 * 2)        // 35684352
#define TOTAL_WS (WPRE_BYTES + TRANS_BYTES)

__device__ __forceinline__ unsigned short f2bf(float x) {
  unsigned u = __float_as_uint(x);
  return (unsigned short)((u + 0x7fffu + ((u >> 16) & 1u)) >> 16);
}
__device__ __forceinline__ unsigned pk2(float a, float b) {
  unsigned ua = __float_as_uint(a), ub = __float_as_uint(b);
  return ((ua + 0x7fffu + ((ua >> 16) & 1u)) >> 16) |
         ((ub + 0x7fffu + ((ub >> 16) & 1u)) & 0xffff0000u);
}
__device__ __forceinline__ bf16x8 ld_frag(const uint4* a) {
  union { uint4 u; bf16x8 s; } cv; cv.u = *a; return cv.s;
}
__device__ __forceinline__ void async16(const void* g, void* l) {
  __builtin_amdgcn_global_load_lds(
      (__attribute__((address_space(1))) void*)(void*)g,
      (__attribute__((address_space(3))) void*)l, 16, 0, 0);
}

// ---------------- fused pre-pass: transform + wprep ------------------------
// grid (102, 32): x < 66 -> padded-NHWC transform of (row hp=x, batch y);
//                 x >= 66 -> wprep: linear elem L = ((x-66)*32+y)*256+tid.
__global__ __launch_bounds__(256) void prep(const float* __restrict__ in,
                                            const float* __restrict__ w,
                                            unsigned short* __restrict__ tp,
                                            unsigned short* __restrict__ wpre) {
  const int tid = threadIdx.x;
  if (blockIdx.x >= 66) {
    // wpre[t][o][pos][e] = W[o][ c=(t&1)*64 + (pos^(o&7))*8 + e ][ tap=t>>1 ]
    const int L   = ((((blockIdx.x - 66) << 5) + blockIdx.y) << 8) + tid;
    const int e   = L & 7;
    const int pos = (L >> 3) & 7;
    const int o   = (L >> 6) & 255;
    const int t   = L >> 14;                        // 0..17
    const int c   = ((t & 1) << 6) + ((pos ^ (o & 7)) << 3) + e;
    wpre[L] = f2bf(w[(o * 128 + c) * 9 + (t >> 1)]);
    return;
  }
  // ---- input transform ----
  __shared__ float lds[128 * 65];
  const int hp = blockIdx.x;   // 0..65 padded row
  const int b  = blockIdx.y;
  uint4* rowp = (uint4*)(tp + (size_t)(b * 66 + hp) * 66 * 128);
  uint4 z; z.x = z.y = z.z = z.w = 0u;
  if (hp == 0 || hp == 65) {                 // zero border rows
    for (int s = tid; s < 1056; s += 256) rowp[s] = z;
    return;
  }
  const int h = hp - 1;
  const float* src = in + ((size_t)b << 19) + (h << 6);
  const int ww4 = (tid & 15) << 2;
  const int c0  = tid >> 4;
#pragma unroll
  for (int pass = 0; pass < 8; ++pass) {
    int c = (pass << 4) + c0;
    float4 v = *(const float4*)(src + ((size_t)c << 12) + ww4);  // coalesced
    float* lp = lds + c * 65 + ww4;
    lp[0] = v.x; lp[1] = v.y; lp[2] = v.z; lp[3] = v.w;
  }
  __syncthreads();
  for (int s = tid; s < 1056; s += 256) {
    if (s < 16 || s >= 1040) { rowp[s] = z; continue; }   // zero border cols
    int idx = s - 16;
    int wq = idx >> 4, c8 = idx & 15;
    const float* lp = lds + (c8 << 3) * 65 + wq;
    uint4 d;
    d.x = pk2(lp[0],   lp[65]);
    d.y = pk2(lp[130], lp[195]);
    d.z = pk2(lp[260], lp[325]);
    d.w = pk2(lp[390], lp[455]);
    rowp[s] = d;
  }
}

// ----------------------------- main kernel ---------------------------------
// A LDS layout (per buffer, 1024 uint4): slot = (p>>4)*128 + (c>>2)*64
//   + (p&15)*4 + ((c&3) ^ (p&3))  — the XOR is folded into the per-lane
//   global SOURCE chunk so global_load_lds dest stays linear (rule #21).
// B LDS layout: slot = o*8 + pos, pos holds chunk pos^(o&7) (baked in wpre).
__global__ __launch_bounds__(512, 1) void sconv_mfma9(
    const unsigned short* __restrict__ tp,   // [32][66][66][128] bf16 padded
    const unsigned short* __restrict__ wpre, // [18][256][64] bf16 pre-swizzled
    const float* __restrict__ bias,
    const int* __restrict__ selh,            // [32][32]
    const int* __restrict__ selw,            // [32][32]
    float* __restrict__ out)                 // [32][256][32][32]
{
  __shared__ uint4 Alds[2][1024];   // patches: 16KB/buf
  __shared__ uint4 Blds[2][2048];   // weights: 32KB/buf
  __shared__ float bias_s[256];

  const int tid = threadIdx.x;
  // XCD-chunked swizzle (T1): 256 = 8 XCDs x 32 consecutive logical blocks
  const int d0  = blockIdx.x;
  const int blk = ((d0 & 7) << 5) | (d0 >> 3);
  const int b   = blk >> 3;                 // batch
  const int y0  = (blk & 7) << 2;           // 4 output rows

  if (tid < 256) bias_s[tid] = bias[tid];

  const int wv = tid >> 6, ln = tid & 63;
  const int lo = ln & 15, hi = ln >> 4;

  // ---- A staging role: thread owns pixel p = tid>>2, lane-chunk q = tid&3
  const int p = tid >> 2;
  const int q = tid & 3;
  int asrc;                         // byte offset of pixel row at tap (0,0)
  {
    const int py = y0 + (p >> 5), px = p & 31;
    asrc = (((b * 66 + 2 * py + selh[(py << 5) | px]) * 66
             + 2 * px + selw[(py << 5) | px]) << 8);
  }
  const int cxor = q ^ (p & 3);     // source chunk low-2 bits (XOR swizzle)
  const char* tbase = (const char*)tp;
  // B staging: fully linear, layout identical to LDS (swizzle baked in wpre)
  const char* wsrc = (const char*)wpre + (((wv << 8) + ln) << 4);

  // ---- MFMA role: wave (wo,wp) owns 64o x 64pix
  const int wo = wv >> 1;           // 4 o-waves x 64 o
  const int wp = wv & 1;            // 2 p-waves x 64 pix

  f32x4 acc[4][4] = {};             // [o-frag][pix-frag]

#define STAGE(BUF, T)                                                         \
  do {                                                                        \
    const int tap_ = (T) >> 1;                                                \
    const int di_  = (tap_ >= 6) ? 2 : ((tap_ >= 3) ? 1 : 0);                 \
    const int dj_  = tap_ - 3 * di_;                                          \
    const int ab_  = asrc + ((di_ * 66 + dj_) << 8) + (((T) & 1) << 7);       \
    /* A: 2 instrs, per-lane source chunk (r<<2)|cxor, linear LDS dest */     \
    async16(tbase + ab_ + (cxor << 4),        &Alds[BUF][(wv << 7)]);         \
    async16(tbase + ab_ + ((4 + cxor) << 4),  &Alds[BUF][(wv << 7) + 64]);    \
    /* B: 4 instrs, linear 32KB */                                            \
    async16(wsrc + ((T) << 15),         &Blds[BUF][(wv << 8)]);               \
    async16(wsrc + ((T) << 15) + 1024,  &Blds[BUF][(wv << 8) + 64]);          \
    async16(wsrc + ((T) << 15) + 2048,  &Blds[BUF][(wv << 8) + 128]);         \
    async16(wsrc + ((T) << 15) + 3072,  &Blds[BUF][(wv << 8) + 192]);         \
  } while (0)

#define COMPUTE(BUF)                                                          \
  do {                                                                        \
    const uint4* A_ = &Alds[BUF][0];                                          \
    const uint4* B_ = &Blds[BUF][0];                                          \
    bf16x8 FW[4][2], FP[4][2];                                                \
    _Pragma("unroll")                                                         \
    for (int f = 0; f < 4; ++f) {                                             \
      const int O = (wo << 6) + (f << 4) + lo;                                \
      const int P = (wp << 6) + (f << 4) + lo;                                \
      _Pragma("unroll")                                                       \
      for (int ks = 0; ks < 2; ++ks) {                                        \
        FW[f][ks] = ld_frag(B_ + (O << 3) + (((ks << 2) | hi) ^ (lo & 7)));   \
        FP[f][ks] = ld_frag(A_ + ((P >> 4) << 7) + (ks << 6)                  \
                            + ((P & 15) << 2) + (hi ^ (P & 3)));              \
      }                                                                       \
    }                                                                         \
    __builtin_amdgcn_s_setprio(1);                                            \
    _Pragma("unroll")                                                         \
    for (int fo = 0; fo < 4; ++fo)                                            \
      _Pragma("unroll")                                                       \
      for (int fp = 0; fp < 4; ++fp)                                          \
        _Pragma("unroll")                                                     \
        for (int ks = 0; ks < 2; ++ks)                                        \
          acc[fo][fp] = __builtin_amdgcn_mfma_f32_16x16x32_bf16(              \
              FW[fo][ks], FP[fp][ks], acc[fo][fp], 0, 0, 0);                  \
    __builtin_amdgcn_s_setprio(0);                                            \
  } while (0)

  // drain setup loads (sel/bias) so the counted vmcnt below is exact
  asm volatile("s_waitcnt vmcnt(0) lgkmcnt(0)" ::: "memory");
  __builtin_amdgcn_s_barrier();
  asm volatile("" ::: "memory");

  STAGE(0, 0);                      // prologue: 6 loads in flight

#pragma unroll
  for (int t = 0; t < 18; ++t) {
    if (t < 17) {
      STAGE((t + 1) & 1, t + 1);                         // 1-step prefetch
      asm volatile("s_waitcnt vmcnt(6)" ::: "memory");   // step-t loads landed
    } else {
      asm volatile("s_waitcnt vmcnt(0)" ::: "memory");
    }
    __builtin_amdgcn_s_barrier();          // all waves' buf[t&1] complete
    asm volatile("" ::: "memory");
    COMPUTE(t & 1);                        // 16 ds_read_b128 + 32 MFMA
    asm volatile("s_waitcnt lgkmcnt(0)" ::: "memory");   // reads retired
    __builtin_amdgcn_s_barrier();          // before buf[t&1] is overwritten
    asm volatile("" ::: "memory");
  }
#undef STAGE
#undef COMPUTE

  // ---- epilogue: D row = o (hi*4+j), col = pix (lo); +bias
  float* ob = out + ((size_t)b << 18) + (y0 << 5);
#pragma unroll
  for (int fo = 0; fo < 4; ++fo) {
    const int obase = (wo << 6) + (fo << 4) + (hi << 2);
#pragma unroll
    for (int fp = 0; fp < 4; ++fp) {
      const int P = (wp << 6) + (fp << 4) + lo;
#pragma unroll
      for (int j = 0; j < 4; ++j) {
        const int o = obase + j;
        ob[((size_t)o << 10) + P] = acc[fo][fp][j] + bias_s[o];
      }
    }
  }
}

// ------------------- exact fp32 fallback (ws too small) --------------------
__global__ __launch_bounds__(256) void sconv_naive(
    const float* __restrict__ in, const float* __restrict__ w,
    const float* __restrict__ bias, const int* __restrict__ selh,
    const int* __restrict__ selw, float* __restrict__ out) {
  int idx = (blockIdx.x << 8) + threadIdx.x;
  if (idx >= 32 * 256 * 32 * 32) return;
  int x = idx & 31, y = (idx >> 5) & 31, o = (idx >> 10) & 255, b = idx >> 18;
  int rh0 = 2 * y + selh[(y << 5) | x] - 1;
  int rw0 = 2 * x + selw[(y << 5) | x] - 1;
  const float* inb = in + ((size_t)b << 19);
  const float* wo_ = w + o * 1152;
  float acc = bias[o];
  for (int c = 0; c < 128; ++c)
    for (int i = 0; i < 3; ++i) {
      int rh = rh0 + i;
      if (rh < 0 || rh >= 64) continue;
      for (int j = 0; j < 3; ++j) {
        int rw = rw0 + j;
        if (rw < 0 || rw >= 64) continue;
        acc += inb[(c << 12) + (rh << 6) + rw] * wo_[c * 9 + i * 3 + j];
      }
    }
  out[idx] = acc;
}

extern "C" void kernel_launch(void* const* d_in, const int* in_sizes, int n_in,
                              void* d_out, int out_size, void* d_ws, size_t ws_size,
                              hipStream_t stream) {
  const float* in   = (const float*)d_in[0];
  const float* w    = (const float*)d_in[1];
  const float* bias = (const float*)d_in[2];
  const int*   selh = (const int*)d_in[3];
  const int*   selw = (const int*)d_in[4];
  float* out = (float*)d_out;

  if (ws_size >= (size_t)TOTAL_WS) {
    unsigned short* wpre = (unsigned short*)d_ws;
    unsigned short* tp   = (unsigned short*)((char*)d_ws + WPRE_BYTES);
    prep<<<dim3(102, 32), dim3(256), 0, stream>>>(in, w, tp, wpre);
    sconv_mfma9<<<dim3(256), dim3(512), 0, stream>>>(tp, wpre, bias, selh, selw, out);
  } else {
    sconv_naive<<<dim3(32768), dim3(256), 0, stream>>>(in, w, bias, selh, selw, out);
  }
}